// Round 8
// baseline (213.970 us; speedup 1.0000x reference)
//
#include <hip/hip_runtime.h>

// ---------------------------------------------------------------------------
// MambaBlock forward, MI355X gfx950.  R7: NC=128/TC=8 (halve serial scan
// chain, double scan parallelism).  Base = R6 (206.6us measured).
// CONTRACT (pinned R4): inputs f32, OUTPUT f32. ws = 256 MiB (pinned R9).
// Internals: bf16 GEMM operands (MFMA 16x16x32), f32 accumulation/scan.
// Session lessons pinned in structure:
//  - R1 LESSON: split-K f32 atomics REGRESSED +14us. Partials+reduce stay.
//  - R2 LESSON: XCD swizzle (T1) + vectorized conv = -6.3us. Kept.
//  - R3 LESSON: fuse reduce into consumer staging + fill all CUs = -3.9us.
//  - R4 LESSON: conv->xproj fusion only -1.2us (reg-staging tax).
//  - R5 LESSON: bf16 on HBM-BW intermediates (GEMM2 partials, hstate)
//    = -6.2us, absmax 0.047->0.0625 (passed).
//  - R6 LESSON: bf16 xpp NEUTRAL — scan staging was L3-resident; scan
//    passes are LATENCY-bound. Byte-compression family exhausted.
//  - R7 (this round): NC 64->128, TC 16->8. R14 showed NC down = worse
//    (serial chains latency-bound); this goes the other way: chain/block
//    halves, scan grid 1024->2048 blocks (~8 blk/CU, max waves), hstate
//    traffic doubles (+16.8MB bf16 ~ +2.7us, cheap per R5/R6 evidence).
//  - 256^2 8-phase GEMM1: NO-GO (128 blocks = 0.5 blk/CU, LDS caps 1/CU;
//    m232 regression at 128^2+8ph). GEMMs structure-capped at m97 shape.
//  - R12: no intra-kernel __threadfence. R11: no cooperative launch.
//  - GEMM: BK=64 as two 128x32 half-buffers, global_load_lds width=16.
// B=2, S=1024, D_MODEL=1024, D_INNER=2048, D_STATE=16, D_CONV=4.
// ---------------------------------------------------------------------------

#define NTOK      2048       // BATCH*SEQ
#define NC        128        // scan chunks per sequence (R7: 64->128)
#define TC        8          // steps per chunk (SEQ/NC)
#define XPP_PARTS 16         // xproj split-K parts

typedef unsigned short u16;
typedef short short8 __attribute__((ext_vector_type(8)));
typedef u16 ushort8v __attribute__((ext_vector_type(8)));
typedef float f32x4 __attribute__((ext_vector_type(4)));

__device__ __forceinline__ float bf2f(u16 v) {
    union { unsigned int u; float f; } w; w.u = ((unsigned int)v) << 16; return w.f;
}
__device__ __forceinline__ u16 f2bf(float f) {
    union { float f; unsigned int u; } w; w.f = f;
    unsigned int u = w.u;
    return (u16)((u + 0x7fffu + ((u >> 16) & 1u)) >> 16);
}

// Async global->LDS, 16B per lane; LDS dst wave-uniform base (m97/m104/m108).
__device__ __forceinline__ void gload_lds16(const u16* g, u16* l) {
    __builtin_amdgcn_global_load_lds(
        (const __attribute__((address_space(1))) void*)g,
        (__attribute__((address_space(3))) void*)l, 16, 0, 0);
}

// fast softplus: max(x,0) + log(1+exp(-|x|))
__device__ __forceinline__ float softplus_f(float x) {
    return fmaxf(x, 0.f) + __logf(1.f + __expf(-__builtin_fabsf(x)));
}

// ---------------------------------------------------------------------------
// Fused prep: block-range dispatch.
//   [0, 2048)        cast x f32 -> bf16 (float4 / 4 elems per thread)
//   [2048, 6144)     transpose W_in  [1024][4096] -> WinT  [4096][1024] bf16
//   [6144, 8192)     transpose W_out [2048][1024] -> WoutT [1024][2048] bf16
//   [8192, 9216)     W_xproj [2048][33] -> WxpT [128][2048] bf16, zero-pad
// ---------------------------------------------------------------------------
__device__ __forceinline__ void transpose_tile(const float* __restrict__ in,
                                               u16* __restrict__ out,
                                               int R, int C, int n0, int k0,
                                               int tid) {
    __shared__ float tile[32][33];
    const int tx = tid & 31, ty = tid >> 5;   // 32x8
    #pragma unroll
    for (int i = 0; i < 32; i += 8)
        tile[ty + i][tx] = in[(size_t)(k0 + ty + i) * C + n0 + tx];
    __syncthreads();
    #pragma unroll
    for (int i = 0; i < 32; i += 8)
        out[(size_t)(n0 + ty + i) * R + k0 + tx] = f2bf(tile[tx][ty + i]);
}

__global__ __launch_bounds__(256)
void prep_all(const float* __restrict__ x, const float* __restrict__ W_in,
              const float* __restrict__ W_out, const float* __restrict__ W_xproj,
              u16* __restrict__ xbf, u16* __restrict__ WinT,
              u16* __restrict__ WoutT, u16* __restrict__ WxpT) {
    const int tid = threadIdx.x;
    int blk = blockIdx.x;
    if (blk < 2048) {                          // cast x (2M elems, 4/thread)
        int base = (blk * 256 + tid) * 4;
        float4 v = *(const float4*)(x + base);
        ushort4 o;
        o.x = f2bf(v.x); o.y = f2bf(v.y); o.z = f2bf(v.z); o.w = f2bf(v.w);
        *(ushort4*)(xbf + base) = o;
        return;
    }
    blk -= 2048;
    if (blk < 4096) {                          // W_in: R=1024, C=4096
        transpose_tile(W_in, WinT, 1024, 4096, (blk & 127) * 32, (blk >> 7) * 32, tid);
        return;
    }
    blk -= 4096;
    if (blk < 2048) {                          // W_out: R=2048, C=1024
        transpose_tile(W_out, WoutT, 2048, 1024, (blk & 31) * 32, (blk >> 5) * 32, tid);
        return;
    }
    blk -= 2048;
    {                                          // WxpT pad+transpose
        int gid = blk * 256 + tid;
        int k = gid & 2047;
        int n = gid >> 11;
        WxpT[(size_t)n * 2048 + k] = (n < 33) ? f2bf(W_xproj[(size_t)k * 33 + n]) : (u16)0;
    }
}

// ---------------------------------------------------------------------------
// MFMA GEMM (R10-verified inner loop): C[M][N] = A[M][K] * Bt[N][K]^T,
// 128x128 tile, BK=64 staged as two 128x32 half-buffers.
// R2: bijective XCD-aware swizzle of the flattened block id (T1); all grids
// have nwg % 8 == 0.
// OUT_MODE: 0 = bf16 partial at bz*M*N (split-K, atomic-free; R5),
//           2 = bf16 store (gridDim.z==1).
// ---------------------------------------------------------------------------
template <int OUT_MODE>
__global__ __launch_bounds__(256)
void gemm_bt(const u16* __restrict__ A, const u16* __restrict__ Bt,
             void* __restrict__ Cv, int M, int N, int K) {
    __shared__ __align__(16) u16 As[2][128 * 32];
    __shared__ __align__(16) u16 Bs[2][128 * 32];

    // ---- XCD swizzle (T1): flat -> chunked-per-XCD, then decode ----
    const unsigned nwg = gridDim.x * gridDim.y * gridDim.z;
    unsigned flat = blockIdx.x + gridDim.x * (blockIdx.y + gridDim.y * blockIdx.z);
    flat = (flat & 7u) * (nwg >> 3) + (flat >> 3);
    const int bx = flat % gridDim.x;
    const unsigned rem = flat / gridDim.x;
    const int by = rem % gridDim.y;
    const int bz = rem / gridDim.y;

    const int tid  = threadIdx.x;
    const int lane = tid & 63;
    const int w    = tid >> 6;
    const int wm   = (w >> 1) * 64;
    const int wn   = (w & 1) * 64;
    const int r    = lane & 15;
    const int q    = lane >> 4;
    const int m0   = bx * 128;
    const int n0   = by * 128;
    const int kChunk = K / gridDim.z;
    const int k0   = bz * kChunk;

    f32x4 acc[4][4];
    #pragma unroll
    for (int i = 0; i < 4; ++i)
        #pragma unroll
        for (int j = 0; j < 4; ++j)
            acc[i][j] = (f32x4){0.f, 0.f, 0.f, 0.f};

    for (int kk = k0; kk < k0 + kChunk; kk += 64) {
        __syncthreads();
        #pragma unroll
        for (int i = 0; i < 4; ++i) {
            int half = i >> 1;
            int c    = ((i & 1) << 8) + tid;
            int row  = c >> 2;
            int kc   = (c & 3) << 3;
            int wb   = (((i & 1) << 8) + (tid & 192)) * 8;
            gload_lds16(&A[(size_t)(m0 + row) * K + kk + half * 32 + kc],
                        &As[half][wb]);
            gload_lds16(&Bt[(size_t)(n0 + row) * K + kk + half * 32 + kc],
                        &Bs[half][wb]);
        }
        __syncthreads();

        #pragma unroll
        for (int half = 0; half < 2; ++half) {
            short8 af[4], bf[4];
            #pragma unroll
            for (int mt = 0; mt < 4; ++mt)
                af[mt] = *(const short8*)(&As[half][(wm + mt * 16 + r) * 32 + q * 8]);
            #pragma unroll
            for (int nt = 0; nt < 4; ++nt)
                bf[nt] = *(const short8*)(&Bs[half][(wn + nt * 16 + r) * 32 + q * 8]);

            #pragma unroll
            for (int mt = 0; mt < 4; ++mt)
                #pragma unroll
                for (int nt = 0; nt < 4; ++nt)
                    acc[mt][nt] = __builtin_amdgcn_mfma_f32_16x16x32_bf16(
                        af[mt], bf[nt], acc[mt][nt], 0, 0, 0);
        }
    }

    u16* Cp = (u16*)Cv + (size_t)bz * M * N;
    #pragma unroll
    for (int mt = 0; mt < 4; ++mt) {
        #pragma unroll
        for (int nt = 0; nt < 4; ++nt) {
            #pragma unroll
            for (int i = 0; i < 4; ++i) {
                int row = m0 + wm + mt * 16 + q * 4 + i;
                int col = n0 + wn + nt * 16 + r;
                float v = acc[mt][nt][i];
                size_t idx = (size_t)row * N + col;
                ((u16*)Cp)[idx] = f2bf(v);   // both modes store bf16
            }
        }
    }
}

// ---------------------------------------------------------------------------
// R4: xproj GEMM with conv+SiLU fused into A-staging.
// C[2048][128] += conv_silu(xz)[M][K] * WxpT[128][K]^T, split-K=16.
// R6: xpp partials bf16 (additive-only).
// ---------------------------------------------------------------------------
__global__ __launch_bounds__(256)
void xproj_conv(const u16* __restrict__ xz, const float* __restrict__ cw,
                const float* __restrict__ cb, const u16* __restrict__ WxpT,
                u16* __restrict__ xcb, u16* __restrict__ xpp) {
    __shared__ __align__(16) u16 As[2][128 * 32];
    __shared__ __align__(16) u16 Bs[2][128 * 32];

    // XCD swizzle over 16x16=256 blocks
    const unsigned nwg = gridDim.x * gridDim.z;
    unsigned flat = blockIdx.x + gridDim.x * blockIdx.z;
    flat = (flat & 7u) * (nwg >> 3) + (flat >> 3);
    const int bx = flat % gridDim.x;
    const int bz = flat / gridDim.x;

    const int tid  = threadIdx.x;
    const int lane = tid & 63;
    const int w    = tid >> 6;
    const int wm   = (w >> 1) * 64;
    const int wn   = (w & 1) * 64;
    const int r    = lane & 15;
    const int q    = lane >> 4;
    const int m0   = bx * 128;
    const int k0   = bz * 128;            // kChunk = 2048/16

    f32x4 acc[4][4];
    #pragma unroll
    for (int i = 0; i < 4; ++i)
        #pragma unroll
        for (int j = 0; j < 4; ++j)
            acc[i][j] = (f32x4){0.f, 0.f, 0.f, 0.f};

    for (int kk = k0; kk < k0 + 128; kk += 64) {
        __syncthreads();
        #pragma unroll
        for (int i = 0; i < 4; ++i) {
            const int half = i >> 1;
            const int c    = ((i & 1) << 8) + tid;
            const int row  = c >> 2;
            const int kc   = (c & 3) << 3;
            // B: async gload (wave-uniform LDS base, unchanged)
            const int wb   = (((i & 1) << 8) + (tid & 192)) * 8;
            gload_lds16(&WxpT[(size_t)row * 2048 + kk + half * 32 + kc],
                        &Bs[half][wb]);
            // A: fused conv+SiLU in registers -> ds_write + xcb store
            const int tok = m0 + row;
            const int b   = tok >> 10;
            const int t   = tok & 1023;
            const int d0  = kk + half * 32 + kc;

            const float4 cb0 = *(const float4*)(cb + d0);
            const float4 cb1 = *(const float4*)(cb + d0 + 4);
            ushort8v v[4];
            #pragma unroll
            for (int j = 0; j < 4; ++j) {
                const int tt = t - 3 + j;
                v[j] = (ushort8v){0, 0, 0, 0, 0, 0, 0, 0};
                if (tt >= 0)
                    v[j] = *(const ushort8v*)(xz + (size_t)(b * 1024 + tt) * 4096 + d0);
            }
            ushort8v o;
            #pragma unroll
            for (int k = 0; k < 8; ++k) {
                const float4 cwk = *(const float4*)(cw + (size_t)(d0 + k) * 4);
                float s = (k < 4) ? ((const float*)&cb0)[k] : ((const float*)&cb1)[k - 4];
                s += bf2f(v[0][k]) * cwk.x;
                s += bf2f(v[1][k]) * cwk.y;
                s += bf2f(v[2][k]) * cwk.z;
                s += bf2f(v[3][k]) * cwk.w;
                const float sl = s / (1.f + __expf(-s));
                o[k] = f2bf(sl);
            }
            *(ushort8v*)(&As[half][(size_t)c * 8]) = o;
            *(ushort8v*)(xcb + (size_t)tok * 2048 + d0) = o;
        }
        __syncthreads();

        #pragma unroll
        for (int half = 0; half < 2; ++half) {
            short8 af[4], bf[4];
            #pragma unroll
            for (int mt = 0; mt < 4; ++mt)
                af[mt] = *(const short8*)(&As[half][(wm + mt * 16 + r) * 32 + q * 8]);
            #pragma unroll
            for (int nt = 0; nt < 4; ++nt)
                bf[nt] = *(const short8*)(&Bs[half][(wn + nt * 16 + r) * 32 + q * 8]);

            #pragma unroll
            for (int mt = 0; mt < 4; ++mt)
                #pragma unroll
                for (int nt = 0; nt < 4; ++nt)
                    acc[mt][nt] = __builtin_amdgcn_mfma_f32_16x16x32_bf16(
                        af[mt], bf[nt], acc[mt][nt], 0, 0, 0);
        }
    }

    u16* Cp = xpp + (size_t)bz * NTOK * 128;
    #pragma unroll
    for (int mt = 0; mt < 4; ++mt) {
        #pragma unroll
        for (int nt = 0; nt < 4; ++nt) {
            #pragma unroll
            for (int i = 0; i < 4; ++i) {
                int row = m0 + wm + mt * 16 + q * 4 + i;
                int col = wn + nt * 16 + r;
                Cp[(size_t)row * 128 + col] = f2bf(acc[mt][nt][i]);
            }
        }
    }
}

// R5: reduce bf16 split-K partials 8-wide: o[8i..8i+7] = sum_z bf2f(p[z][..])
// f32 accumulation, z-ascending (same order as before).
__global__ __launch_bounds__(256)
void reduce_parts_bf16(const u16* __restrict__ p, float* __restrict__ o,
                       int n8, int parts) {
    int i = blockIdx.x * 256 + threadIdx.x;
    if (i >= n8) return;
    float s[8] = {0.f, 0.f, 0.f, 0.f, 0.f, 0.f, 0.f, 0.f};
    for (int z = 0; z < parts; ++z) {
        ushort8v v = ((const ushort8v*)p)[(size_t)z * n8 + i];
        #pragma unroll
        for (int k = 0; k < 8; ++k) s[k] += bf2f(v[k]);
    }
    float4 o0 = make_float4(s[0], s[1], s[2], s[3]);
    float4 o1 = make_float4(s[4], s[5], s[6], s[7]);
    ((float4*)o)[2 * (size_t)i]     = o0;
    ((float4*)o)[2 * (size_t)i + 1] = o1;
}

// dA powers tree: dA[n] = e1^(n+1), dep depth ~3.
__device__ __forceinline__ void pow_tree(float e1, float* dA) {
    float e2 = e1 * e1, e4 = e2 * e2, e8 = e4 * e4;
    dA[0] = e1;       dA[1] = e2;       dA[2] = e2 * e1;  dA[3] = e4;
    dA[4] = e4 * e1;  dA[5] = e4 * e2;  dA[6] = e4 * dA[2]; dA[7] = e8;
    dA[8] = e8 * e1;  dA[9] = e8 * e2;  dA[10] = e8 * dA[2]; dA[11] = e8 * e4;
    dA[12] = e8 * dA[4]; dA[13] = e8 * dA[5]; dA[14] = e8 * dA[6]; dA[15] = e8 * e8;
}

// Fused xpp staging + split-K reduce into LDS (R3/R6): bf16 partials,
// f32 accum z-ascending.  xpp layout: [z][tok][128] bf16; [0]=dt_raw,
// [1..16]=B, [17..32]=C.  (magic /33 valid for e < 528; TC*33 = 264.)
__device__ __forceinline__ void stage_xp(const u16* __restrict__ xpp,
                                         float (*xps)[36], int tok0, int tid) {
    for (int e = tid; e < TC * 33; e += 256) {
        int t = (e * 993) >> 15;     // e/33 for e<528
        int j = e - t * 33;
        const u16* pp = xpp + (size_t)(tok0 + t) * 128 + j;
        float s = 0.f;
        #pragma unroll
        for (int z = 0; z < XPP_PARTS; ++z)
            s += bf2f(pp[(size_t)z * NTOK * 128]);
        xps[t][j] = s;
    }
}

// ---------------------------------------------------------------------------
// Chunked selective scan (R10-verified math). Lanes over d; 16 states in
// regs; xp tile in LDS. R7: NC=128/TC=8 — 2048 blocks/pass (~8 blk/CU),
// serial chain halved. R5: hend/hstart bf16 (f32 compute, round at store).
// ---------------------------------------------------------------------------
__global__ __launch_bounds__(256)
void scan_pass1(const u16* __restrict__ xcb, const u16* __restrict__ xpp,
                const float* __restrict__ W_dt, const float* __restrict__ b_dt,
                const float* __restrict__ A_log,
                float* __restrict__ Sdl, u16* __restrict__ hend) {
    const int c  = blockIdx.x;
    const int dg = blockIdx.y;
    const int b  = blockIdx.z;
    const int tid = threadIdx.x;
    const int d  = dg * 256 + tid;
    const int tok0 = b * 1024 + c * TC;

    __shared__ float xps[TC][36];
    stage_xp(xpp, xps, tok0, tid);
    __syncthreads();

    float a[16];
    bool fast = true;
    #pragma unroll
    for (int n = 0; n < 16; ++n) {
        a[n] = -__expf(A_log[n]);
        fast = fast && (__builtin_fabsf(a[n] + (float)(n + 1)) < 1e-3f * (n + 1));
    }

    const float wdt = W_dt[d];
    const float bdt = b_dt[d];

    float h[16];
    #pragma unroll
    for (int n = 0; n < 16; ++n) h[n] = 0.f;
    float sdl = 0.f;

    for (int t = 0; t < TC; ++t) {
        const int tok = tok0 + t;
        const float dl = softplus_f(xps[t][0] * wdt + bdt);
        sdl += dl;
        const float xv = bf2f(xcb[(size_t)tok * 2048 + d]);
        const float wv = dl * xv;
        if (fast) {
            float dA[16];
            pow_tree(__expf(-dl), dA);
            #pragma unroll
            for (int n = 0; n < 16; ++n)
                h[n] = fmaf(dA[n], h[n], wv * xps[t][1 + n]);
        } else {
            #pragma unroll
            for (int n = 0; n < 16; ++n)
                h[n] = fmaf(__expf(dl * a[n]), h[n], wv * xps[t][1 + n]);
        }
    }

    Sdl[(size_t)(b * NC + c) * 2048 + d] = sdl;
    #pragma unroll
    for (int n = 0; n < 16; ++n)
        hend[((size_t)((b * NC + c) * 16 + n)) * 2048 + d] = f2bf(h[n]);
}

// Sequential combine (coalesced over d); alias-free in/out (R10).
// R5: bf16 hend/hstart; H accum stays f32 (no compounding).
// R6: 128 blocks x 128 threads. R7: NC=128 iters (chain ~1.6us, fine).
__global__ __launch_bounds__(128)
void scan_combine(const float* __restrict__ Sdl, const float* __restrict__ A_log,
                  const u16* __restrict__ hend, u16* __restrict__ hstart) {
    const int gid = blockIdx.x * 128 + threadIdx.x;   // 16384 lanes (x4 d)
    const int d4 = gid & 511;
    const int n  = (gid >> 9) & 15;
    const int b  = gid >> 13;
    const float an = -__expf(A_log[n]);
    float H0 = 0.f, H1 = 0.f, H2 = 0.f, H3 = 0.f;
    #pragma unroll 4
    for (int c = 0; c < NC; ++c) {
        size_t cidx = (size_t)(b * NC + c);
        float4 s  = ((const float4*)Sdl)[cidx * 512 + d4];
        size_t idx = (cidx * 16 + n) * 512 + d4;
        ushort4 he = ((const ushort4*)hend)[idx];
        ushort4 hs;
        hs.x = f2bf(H0); hs.y = f2bf(H1); hs.z = f2bf(H2); hs.w = f2bf(H3);
        ((ushort4*)hstart)[idx] = hs;              // start state for chunk c
        H0 = fmaf(__expf(an * s.x), H0, bf2f(he.x));
        H1 = fmaf(__expf(an * s.y), H1, bf2f(he.y));
        H2 = fmaf(__expf(an * s.z), H2, bf2f(he.z));
        H3 = fmaf(__expf(an * s.w), H3, bf2f(he.w));
    }
}

__global__ __launch_bounds__(256)
void scan_pass2(const u16* __restrict__ xcb, const u16* __restrict__ xpp,
                const float* __restrict__ W_dt, const float* __restrict__ b_dt,
                const float* __restrict__ A_log, const u16* __restrict__ Hstart,
                const float* __restrict__ Dp, const u16* __restrict__ xz,
                u16* __restrict__ ybuf) {
    const int c  = blockIdx.x;
    const int dg = blockIdx.y;
    const int b  = blockIdx.z;
    const int tid = threadIdx.x;
    const int d  = dg * 256 + tid;
    const int tok0 = b * 1024 + c * TC;

    __shared__ float xps[TC][36];
    stage_xp(xpp, xps, tok0, tid);
    __syncthreads();

    float a[16];
    bool fast = true;
    #pragma unroll
    for (int n = 0; n < 16; ++n) {
        a[n] = -__expf(A_log[n]);
        fast = fast && (__builtin_fabsf(a[n] + (float)(n + 1)) < 1e-3f * (n + 1));
    }

    const float wdt = W_dt[d];
    const float bdt = b_dt[d];

    float h[16];
    #pragma unroll
    for (int n = 0; n < 16; ++n)
        h[n] = bf2f(Hstart[((size_t)((b * NC + c) * 16 + n)) * 2048 + d]);

    const float Dd = Dp[d];
    for (int t = 0; t < TC; ++t) {
        const int tok = tok0 + t;
        const float dl = softplus_f(xps[t][0] * wdt + bdt);
        const float xv = bf2f(xcb[(size_t)tok * 2048 + d]);
        const float wv = dl * xv;
        if (fast) {
            float dA[16];
            pow_tree(__expf(-dl), dA);
            #pragma unroll
            for (int n = 0; n < 16; ++n)
                h[n] = fmaf(dA[n], h[n], wv * xps[t][1 + n]);
        } else {
            #pragma unroll
            for (int n = 0; n < 16; ++n)
                h[n] = fmaf(__expf(dl * a[n]), h[n], wv * xps[t][1 + n]);
        }
        float y0 = 0.f, y1 = 0.f, y2 = 0.f, y3 = 0.f;
        #pragma unroll
        for (int n = 0; n < 16; n += 4) {
            y0 = fmaf(h[n + 0], xps[t][17 + n + 0], y0);
            y1 = fmaf(h[n + 1], xps[t][17 + n + 1], y1);
            y2 = fmaf(h[n + 2], xps[t][17 + n + 2], y2);
            y3 = fmaf(h[n + 3], xps[t][17 + n + 3], y3);
        }
        float y = (y0 + y1) + (y2 + y3);
        y = fmaf(Dd, xv, y);
        float zv = bf2f(xz[(size_t)tok * 4096 + 2048 + d]);
        float sz = zv / (1.f + __expf(-zv));
        ybuf[(size_t)tok * 2048 + d] = f2bf(y * sz);
    }
}

// ---------------------------------------------------------------------------
extern "C" void kernel_launch(void* const* d_in, const int* in_sizes, int n_in,
                              void* d_out, int out_size, void* d_ws, size_t ws_size,
                              hipStream_t stream) {
    const float* x       = (const float*)d_in[0];
    const float* W_in    = (const float*)d_in[1];
    const float* conv_w  = (const float*)d_in[2];
    const float* conv_b  = (const float*)d_in[3];
    const float* W_xproj = (const float*)d_in[4];
    const float* W_dt    = (const float*)d_in[5];
    const float* b_dt    = (const float*)d_in[6];
    const float* A_log   = (const float*)d_in[7];
    const float* Dp      = (const float*)d_in[8];
    const float* W_out   = (const float*)d_in[9];
    float* out = (float*)d_out;                     // [2][1024][1024] f32

    char* ws = (char*)d_ws;
    size_t off = 0;
    auto alloc = [&](size_t bytes) -> void* {
        void* p = ws + off;
        off += (bytes + 255) & ~(size_t)255;
        return p;
    };

    u16*   xbf    = (u16*)  alloc((size_t)NTOK * 1024 * 2);
    u16*   xz     = (u16*)  alloc((size_t)NTOK * 4096 * 2);
    u16*   WinT   = (u16*)  alloc((size_t)4096 * 1024 * 2);
    u16*   WoutT  = (u16*)  alloc((size_t)1024 * 2048 * 2);
    u16*   WxpT   = (u16*)  alloc((size_t)128 * 2048 * 2);
    u16*   xcb    = (u16*)  alloc((size_t)NTOK * 2048 * 2);
    u16*   xpp    = (u16*)  alloc((size_t)XPP_PARTS * NTOK * 128 * 2); // 8.4 MB
    u16*   ybuf   = (u16*)  alloc((size_t)NTOK * 2048 * 2);
    float* Sdl    = (float*)alloc((size_t)2 * NC * 2048 * 4);          //  2.1 MB
    u16*   hend   = (u16*)  alloc((size_t)2 * NC * 16 * 2048 * 2);     // 16.8 MB
    u16*   hstart = (u16*)  alloc((size_t)2 * NC * 16 * 2048 * 2);     // 16.8 MB
    u16*   op     = (u16*)  alloc((size_t)4 * NTOK * 1024 * 2);        // 16.8 MB

    const int ws_ok = (off <= ws_size);   // ws = 256 MiB; total ~105 MB
    if (ws_ok) {
        // fused prep: cast x (float4), transpose W_in/W_out, pad W_xproj
        prep_all<<<9216, 256, 0, stream>>>(x, W_in, W_out, W_xproj,
                                           xbf, WinT, WoutT, WxpT);

        // GEMM1: xz = xbf @ W_in (bf16 out), 512 blocks, 16 K-rounds
        gemm_bt<2><<<dim3(16, 32, 1), 256, 0, stream>>>(xbf, WinT, xz,
                                                        2048, 4096, 1024);

        // xproj with fused conv+SiLU (R4): writes xcb + bf16 xpp partials.
        xproj_conv<<<dim3(16, 1, XPP_PARTS), 256, 0, stream>>>(
            xz, conv_w, conv_b, WxpT, xcb, xpp);

        // chunked scan (R7: NC=128 -> 2048 blocks/pass, ~8 blk/CU)
        scan_pass1<<<dim3(NC, 8, 2), 256, 0, stream>>>(xcb, xpp, W_dt, b_dt, A_log,
                                                       Sdl, hend);
        scan_combine<<<128, 128, 0, stream>>>(Sdl, A_log, hend, hstart);
        scan_pass2<<<dim3(NC, 8, 2), 256, 0, stream>>>(xcb, xpp, W_dt, b_dt, A_log,
                                                       hstart, Dp, xz, ybuf);

        // GEMM2: split-K=4 bf16 partials (R5), then bf16 reduce into d_out
        gemm_bt<0><<<dim3(16, 8, 4), 256, 0, stream>>>(ybuf, WoutT, op,
                                                       2048, 1024, 2048);
        reduce_parts_bf16<<<(NTOK * 1024 / 8) / 256, 256, 0, stream>>>(
            op, out, NTOK * 1024 / 8, 4);
    }
}

// Round 9
// 206.093 us; speedup vs baseline: 1.0382x; 1.0382x over previous
//
#include <hip/hip_runtime.h>

// ---------------------------------------------------------------------------
// MambaBlock forward, MI355X gfx950.  R8: REVERT to R6 config (206.6us) —
// NC=64/TC=16.  R7 (NC=128) regressed +7.4us.
// CONTRACT (pinned R4): inputs f32, OUTPUT f32. ws = 256 MiB (pinned R9).
// Internals: bf16 GEMM operands (MFMA 16x16x32), f32 accumulation/scan.
// Session lessons pinned in structure:
//  - R1 LESSON: split-K f32 atomics REGRESSED +14us. Partials+reduce stay.
//  - R2 LESSON: XCD swizzle (T1) + vectorized conv = -6.3us. Kept.
//  - R3 LESSON: fuse reduce into consumer staging + fill all CUs = -3.9us.
//  - R4 LESSON: conv->xproj fusion only -1.2us (reg-staging tax).
//  - R5 LESSON: bf16 on HBM-BW intermediates (GEMM2 partials, hstate)
//    = -6.2us, absmax 0.047->0.0625 (passed).
//  - R6 LESSON: bf16 xpp NEUTRAL — scan staging is L3-resident; scan
//    passes are per-block-overhead bound, not BW bound.
//  - R7 LESSON: NC=128 REGRESSED +7.4us. Chunk-count curve bracketed:
//    NC=32 +4.3 (R14), NC=64 OPT, NC=128 +7.4. Scan cost = per-block
//    fixed overhead (staging, state I/O) x blocks + serial chain; NC=64
//    is the balance point. SCAN FAMILY CLOSED.
//  - 256^2 8-phase GEMM1: NO-GO (0.5 blk/CU at our shapes; m232 regression
//    at 128^2+8ph). GEMMs structure-capped at m97 shape.
//  - R12: no intra-kernel __threadfence. R11: no cooperative launch.
//  - GEMM: BK=64 as two 128x32 half-buffers, global_load_lds width=16.
// B=2, S=1024, D_MODEL=1024, D_INNER=2048, D_STATE=16, D_CONV=4.
// ---------------------------------------------------------------------------

#define NTOK      2048       // BATCH*SEQ
#define NC        64         // scan chunks per sequence (R8: revert to 64)
#define TC        16         // steps per chunk (SEQ/NC)
#define XPP_PARTS 16         // xproj split-K parts

typedef unsigned short u16;
typedef short short8 __attribute__((ext_vector_type(8)));
typedef u16 ushort8v __attribute__((ext_vector_type(8)));
typedef float f32x4 __attribute__((ext_vector_type(4)));

__device__ __forceinline__ float bf2f(u16 v) {
    union { unsigned int u; float f; } w; w.u = ((unsigned int)v) << 16; return w.f;
}
__device__ __forceinline__ u16 f2bf(float f) {
    union { float f; unsigned int u; } w; w.f = f;
    unsigned int u = w.u;
    return (u16)((u + 0x7fffu + ((u >> 16) & 1u)) >> 16);
}

// Async global->LDS, 16B per lane; LDS dst wave-uniform base (m97/m104/m108).
__device__ __forceinline__ void gload_lds16(const u16* g, u16* l) {
    __builtin_amdgcn_global_load_lds(
        (const __attribute__((address_space(1))) void*)g,
        (__attribute__((address_space(3))) void*)l, 16, 0, 0);
}

// fast softplus: max(x,0) + log(1+exp(-|x|))
__device__ __forceinline__ float softplus_f(float x) {
    return fmaxf(x, 0.f) + __logf(1.f + __expf(-__builtin_fabsf(x)));
}

// ---------------------------------------------------------------------------
// Fused prep: block-range dispatch.
//   [0, 2048)        cast x f32 -> bf16 (float4 / 4 elems per thread)
//   [2048, 6144)     transpose W_in  [1024][4096] -> WinT  [4096][1024] bf16
//   [6144, 8192)     transpose W_out [2048][1024] -> WoutT [1024][2048] bf16
//   [8192, 9216)     W_xproj [2048][33] -> WxpT [128][2048] bf16, zero-pad
// ---------------------------------------------------------------------------
__device__ __forceinline__ void transpose_tile(const float* __restrict__ in,
                                               u16* __restrict__ out,
                                               int R, int C, int n0, int k0,
                                               int tid) {
    __shared__ float tile[32][33];
    const int tx = tid & 31, ty = tid >> 5;   // 32x8
    #pragma unroll
    for (int i = 0; i < 32; i += 8)
        tile[ty + i][tx] = in[(size_t)(k0 + ty + i) * C + n0 + tx];
    __syncthreads();
    #pragma unroll
    for (int i = 0; i < 32; i += 8)
        out[(size_t)(n0 + ty + i) * R + k0 + tx] = f2bf(tile[tx][ty + i]);
}

__global__ __launch_bounds__(256)
void prep_all(const float* __restrict__ x, const float* __restrict__ W_in,
              const float* __restrict__ W_out, const float* __restrict__ W_xproj,
              u16* __restrict__ xbf, u16* __restrict__ WinT,
              u16* __restrict__ WoutT, u16* __restrict__ WxpT) {
    const int tid = threadIdx.x;
    int blk = blockIdx.x;
    if (blk < 2048) {                          // cast x (2M elems, 4/thread)
        int base = (blk * 256 + tid) * 4;
        float4 v = *(const float4*)(x + base);
        ushort4 o;
        o.x = f2bf(v.x); o.y = f2bf(v.y); o.z = f2bf(v.z); o.w = f2bf(v.w);
        *(ushort4*)(xbf + base) = o;
        return;
    }
    blk -= 2048;
    if (blk < 4096) {                          // W_in: R=1024, C=4096
        transpose_tile(W_in, WinT, 1024, 4096, (blk & 127) * 32, (blk >> 7) * 32, tid);
        return;
    }
    blk -= 4096;
    if (blk < 2048) {                          // W_out: R=2048, C=1024
        transpose_tile(W_out, WoutT, 2048, 1024, (blk & 31) * 32, (blk >> 5) * 32, tid);
        return;
    }
    blk -= 2048;
    {                                          // WxpT pad+transpose
        int gid = blk * 256 + tid;
        int k = gid & 2047;
        int n = gid >> 11;
        WxpT[(size_t)n * 2048 + k] = (n < 33) ? f2bf(W_xproj[(size_t)k * 33 + n]) : (u16)0;
    }
}

// ---------------------------------------------------------------------------
// MFMA GEMM (R10-verified inner loop): C[M][N] = A[M][K] * Bt[N][K]^T,
// 128x128 tile, BK=64 staged as two 128x32 half-buffers.
// R2: bijective XCD-aware swizzle of the flattened block id (T1); all grids
// have nwg % 8 == 0.
// OUT_MODE: 0 = bf16 partial at bz*M*N (split-K, atomic-free; R5),
//           2 = bf16 store (gridDim.z==1).
// ---------------------------------------------------------------------------
template <int OUT_MODE>
__global__ __launch_bounds__(256)
void gemm_bt(const u16* __restrict__ A, const u16* __restrict__ Bt,
             void* __restrict__ Cv, int M, int N, int K) {
    __shared__ __align__(16) u16 As[2][128 * 32];
    __shared__ __align__(16) u16 Bs[2][128 * 32];

    // ---- XCD swizzle (T1): flat -> chunked-per-XCD, then decode ----
    const unsigned nwg = gridDim.x * gridDim.y * gridDim.z;
    unsigned flat = blockIdx.x + gridDim.x * (blockIdx.y + gridDim.y * blockIdx.z);
    flat = (flat & 7u) * (nwg >> 3) + (flat >> 3);
    const int bx = flat % gridDim.x;
    const unsigned rem = flat / gridDim.x;
    const int by = rem % gridDim.y;
    const int bz = rem / gridDim.y;

    const int tid  = threadIdx.x;
    const int lane = tid & 63;
    const int w    = tid >> 6;
    const int wm   = (w >> 1) * 64;
    const int wn   = (w & 1) * 64;
    const int r    = lane & 15;
    const int q    = lane >> 4;
    const int m0   = bx * 128;
    const int n0   = by * 128;
    const int kChunk = K / gridDim.z;
    const int k0   = bz * kChunk;

    f32x4 acc[4][4];
    #pragma unroll
    for (int i = 0; i < 4; ++i)
        #pragma unroll
        for (int j = 0; j < 4; ++j)
            acc[i][j] = (f32x4){0.f, 0.f, 0.f, 0.f};

    for (int kk = k0; kk < k0 + kChunk; kk += 64) {
        __syncthreads();
        #pragma unroll
        for (int i = 0; i < 4; ++i) {
            int half = i >> 1;
            int c    = ((i & 1) << 8) + tid;
            int row  = c >> 2;
            int kc   = (c & 3) << 3;
            int wb   = (((i & 1) << 8) + (tid & 192)) * 8;
            gload_lds16(&A[(size_t)(m0 + row) * K + kk + half * 32 + kc],
                        &As[half][wb]);
            gload_lds16(&Bt[(size_t)(n0 + row) * K + kk + half * 32 + kc],
                        &Bs[half][wb]);
        }
        __syncthreads();

        #pragma unroll
        for (int half = 0; half < 2; ++half) {
            short8 af[4], bf[4];
            #pragma unroll
            for (int mt = 0; mt < 4; ++mt)
                af[mt] = *(const short8*)(&As[half][(wm + mt * 16 + r) * 32 + q * 8]);
            #pragma unroll
            for (int nt = 0; nt < 4; ++nt)
                bf[nt] = *(const short8*)(&Bs[half][(wn + nt * 16 + r) * 32 + q * 8]);

            #pragma unroll
            for (int mt = 0; mt < 4; ++mt)
                #pragma unroll
                for (int nt = 0; nt < 4; ++nt)
                    acc[mt][nt] = __builtin_amdgcn_mfma_f32_16x16x32_bf16(
                        af[mt], bf[nt], acc[mt][nt], 0, 0, 0);
        }
    }

    u16* Cp = (u16*)Cv + (size_t)bz * M * N;
    #pragma unroll
    for (int mt = 0; mt < 4; ++mt) {
        #pragma unroll
        for (int nt = 0; nt < 4; ++nt) {
            #pragma unroll
            for (int i = 0; i < 4; ++i) {
                int row = m0 + wm + mt * 16 + q * 4 + i;
                int col = n0 + wn + nt * 16 + r;
                float v = acc[mt][nt][i];
                size_t idx = (size_t)row * N + col;
                ((u16*)Cp)[idx] = f2bf(v);   // both modes store bf16
            }
        }
    }
}

// ---------------------------------------------------------------------------
// R4: xproj GEMM with conv+SiLU fused into A-staging.
// C[2048][128] += conv_silu(xz)[M][K] * WxpT[128][K]^T, split-K=16.
// R6: xpp partials bf16 (additive-only).
// ---------------------------------------------------------------------------
__global__ __launch_bounds__(256)
void xproj_conv(const u16* __restrict__ xz, const float* __restrict__ cw,
                const float* __restrict__ cb, const u16* __restrict__ WxpT,
                u16* __restrict__ xcb, u16* __restrict__ xpp) {
    __shared__ __align__(16) u16 As[2][128 * 32];
    __shared__ __align__(16) u16 Bs[2][128 * 32];

    // XCD swizzle over 16x16=256 blocks
    const unsigned nwg = gridDim.x * gridDim.z;
    unsigned flat = blockIdx.x + gridDim.x * blockIdx.z;
    flat = (flat & 7u) * (nwg >> 3) + (flat >> 3);
    const int bx = flat % gridDim.x;
    const int bz = flat / gridDim.x;

    const int tid  = threadIdx.x;
    const int lane = tid & 63;
    const int w    = tid >> 6;
    const int wm   = (w >> 1) * 64;
    const int wn   = (w & 1) * 64;
    const int r    = lane & 15;
    const int q    = lane >> 4;
    const int m0   = bx * 128;
    const int k0   = bz * 128;            // kChunk = 2048/16

    f32x4 acc[4][4];
    #pragma unroll
    for (int i = 0; i < 4; ++i)
        #pragma unroll
        for (int j = 0; j < 4; ++j)
            acc[i][j] = (f32x4){0.f, 0.f, 0.f, 0.f};

    for (int kk = k0; kk < k0 + 128; kk += 64) {
        __syncthreads();
        #pragma unroll
        for (int i = 0; i < 4; ++i) {
            const int half = i >> 1;
            const int c    = ((i & 1) << 8) + tid;
            const int row  = c >> 2;
            const int kc   = (c & 3) << 3;
            // B: async gload (wave-uniform LDS base, unchanged)
            const int wb   = (((i & 1) << 8) + (tid & 192)) * 8;
            gload_lds16(&WxpT[(size_t)row * 2048 + kk + half * 32 + kc],
                        &Bs[half][wb]);
            // A: fused conv+SiLU in registers -> ds_write + xcb store
            const int tok = m0 + row;
            const int b   = tok >> 10;
            const int t   = tok & 1023;
            const int d0  = kk + half * 32 + kc;

            const float4 cb0 = *(const float4*)(cb + d0);
            const float4 cb1 = *(const float4*)(cb + d0 + 4);
            ushort8v v[4];
            #pragma unroll
            for (int j = 0; j < 4; ++j) {
                const int tt = t - 3 + j;
                v[j] = (ushort8v){0, 0, 0, 0, 0, 0, 0, 0};
                if (tt >= 0)
                    v[j] = *(const ushort8v*)(xz + (size_t)(b * 1024 + tt) * 4096 + d0);
            }
            ushort8v o;
            #pragma unroll
            for (int k = 0; k < 8; ++k) {
                const float4 cwk = *(const float4*)(cw + (size_t)(d0 + k) * 4);
                float s = (k < 4) ? ((const float*)&cb0)[k] : ((const float*)&cb1)[k - 4];
                s += bf2f(v[0][k]) * cwk.x;
                s += bf2f(v[1][k]) * cwk.y;
                s += bf2f(v[2][k]) * cwk.z;
                s += bf2f(v[3][k]) * cwk.w;
                const float sl = s / (1.f + __expf(-s));
                o[k] = f2bf(sl);
            }
            *(ushort8v*)(&As[half][(size_t)c * 8]) = o;
            *(ushort8v*)(xcb + (size_t)tok * 2048 + d0) = o;
        }
        __syncthreads();

        #pragma unroll
        for (int half = 0; half < 2; ++half) {
            short8 af[4], bf[4];
            #pragma unroll
            for (int mt = 0; mt < 4; ++mt)
                af[mt] = *(const short8*)(&As[half][(wm + mt * 16 + r) * 32 + q * 8]);
            #pragma unroll
            for (int nt = 0; nt < 4; ++nt)
                bf[nt] = *(const short8*)(&Bs[half][(wn + nt * 16 + r) * 32 + q * 8]);

            #pragma unroll
            for (int mt = 0; mt < 4; ++mt)
                #pragma unroll
                for (int nt = 0; nt < 4; ++nt)
                    acc[mt][nt] = __builtin_amdgcn_mfma_f32_16x16x32_bf16(
                        af[mt], bf[nt], acc[mt][nt], 0, 0, 0);
        }
    }

    u16* Cp = xpp + (size_t)bz * NTOK * 128;
    #pragma unroll
    for (int mt = 0; mt < 4; ++mt) {
        #pragma unroll
        for (int nt = 0; nt < 4; ++nt) {
            #pragma unroll
            for (int i = 0; i < 4; ++i) {
                int row = m0 + wm + mt * 16 + q * 4 + i;
                int col = wn + nt * 16 + r;
                Cp[(size_t)row * 128 + col] = f2bf(acc[mt][nt][i]);
            }
        }
    }
}

// R5: reduce bf16 split-K partials 8-wide: o[8i..8i+7] = sum_z bf2f(p[z][..])
// f32 accumulation, z-ascending (same order as before).
__global__ __launch_bounds__(256)
void reduce_parts_bf16(const u16* __restrict__ p, float* __restrict__ o,
                       int n8, int parts) {
    int i = blockIdx.x * 256 + threadIdx.x;
    if (i >= n8) return;
    float s[8] = {0.f, 0.f, 0.f, 0.f, 0.f, 0.f, 0.f, 0.f};
    for (int z = 0; z < parts; ++z) {
        ushort8v v = ((const ushort8v*)p)[(size_t)z * n8 + i];
        #pragma unroll
        for (int k = 0; k < 8; ++k) s[k] += bf2f(v[k]);
    }
    float4 o0 = make_float4(s[0], s[1], s[2], s[3]);
    float4 o1 = make_float4(s[4], s[5], s[6], s[7]);
    ((float4*)o)[2 * (size_t)i]     = o0;
    ((float4*)o)[2 * (size_t)i + 1] = o1;
}

// dA powers tree: dA[n] = e1^(n+1), dep depth ~3.
__device__ __forceinline__ void pow_tree(float e1, float* dA) {
    float e2 = e1 * e1, e4 = e2 * e2, e8 = e4 * e4;
    dA[0] = e1;       dA[1] = e2;       dA[2] = e2 * e1;  dA[3] = e4;
    dA[4] = e4 * e1;  dA[5] = e4 * e2;  dA[6] = e4 * dA[2]; dA[7] = e8;
    dA[8] = e8 * e1;  dA[9] = e8 * e2;  dA[10] = e8 * dA[2]; dA[11] = e8 * e4;
    dA[12] = e8 * dA[4]; dA[13] = e8 * dA[5]; dA[14] = e8 * dA[6]; dA[15] = e8 * e8;
}

// Fused xpp staging + split-K reduce into LDS (R3/R6): bf16 partials,
// f32 accum z-ascending.  xpp layout: [z][tok][128] bf16; [0]=dt_raw,
// [1..16]=B, [17..32]=C.  (magic /33 valid for e < 528; TC*33 = 528.)
__device__ __forceinline__ void stage_xp(const u16* __restrict__ xpp,
                                         float (*xps)[36], int tok0, int tid) {
    for (int e = tid; e < TC * 33; e += 256) {
        int t = (e * 993) >> 15;     // e/33 for e<528
        int j = e - t * 33;
        const u16* pp = xpp + (size_t)(tok0 + t) * 128 + j;
        float s = 0.f;
        #pragma unroll
        for (int z = 0; z < XPP_PARTS; ++z)
            s += bf2f(pp[(size_t)z * NTOK * 128]);
        xps[t][j] = s;
    }
}

// ---------------------------------------------------------------------------
// Chunked selective scan (R10-verified math). Lanes over d; 16 states in
// regs; xp tile in LDS. NC=64/TC=16 (R8 revert — bracketed optimum).
// R5: hend/hstart bf16 (f32 compute, round at store).
// ---------------------------------------------------------------------------
__global__ __launch_bounds__(256)
void scan_pass1(const u16* __restrict__ xcb, const u16* __restrict__ xpp,
                const float* __restrict__ W_dt, const float* __restrict__ b_dt,
                const float* __restrict__ A_log,
                float* __restrict__ Sdl, u16* __restrict__ hend) {
    const int c  = blockIdx.x;
    const int dg = blockIdx.y;
    const int b  = blockIdx.z;
    const int tid = threadIdx.x;
    const int d  = dg * 256 + tid;
    const int tok0 = b * 1024 + c * TC;

    __shared__ float xps[TC][36];
    stage_xp(xpp, xps, tok0, tid);
    __syncthreads();

    float a[16];
    bool fast = true;
    #pragma unroll
    for (int n = 0; n < 16; ++n) {
        a[n] = -__expf(A_log[n]);
        fast = fast && (__builtin_fabsf(a[n] + (float)(n + 1)) < 1e-3f * (n + 1));
    }

    const float wdt = W_dt[d];
    const float bdt = b_dt[d];

    float h[16];
    #pragma unroll
    for (int n = 0; n < 16; ++n) h[n] = 0.f;
    float sdl = 0.f;

    for (int t = 0; t < TC; ++t) {
        const int tok = tok0 + t;
        const float dl = softplus_f(xps[t][0] * wdt + bdt);
        sdl += dl;
        const float xv = bf2f(xcb[(size_t)tok * 2048 + d]);
        const float wv = dl * xv;
        if (fast) {
            float dA[16];
            pow_tree(__expf(-dl), dA);
            #pragma unroll
            for (int n = 0; n < 16; ++n)
                h[n] = fmaf(dA[n], h[n], wv * xps[t][1 + n]);
        } else {
            #pragma unroll
            for (int n = 0; n < 16; ++n)
                h[n] = fmaf(__expf(dl * a[n]), h[n], wv * xps[t][1 + n]);
        }
    }

    Sdl[(size_t)(b * NC + c) * 2048 + d] = sdl;
    #pragma unroll
    for (int n = 0; n < 16; ++n)
        hend[((size_t)((b * NC + c) * 16 + n)) * 2048 + d] = f2bf(h[n]);
}

// Sequential combine (coalesced over d); alias-free in/out (R10).
// R5: bf16 hend/hstart; H accum stays f32 (no compounding).
// R6: 128 blocks x 128 threads.
__global__ __launch_bounds__(128)
void scan_combine(const float* __restrict__ Sdl, const float* __restrict__ A_log,
                  const u16* __restrict__ hend, u16* __restrict__ hstart) {
    const int gid = blockIdx.x * 128 + threadIdx.x;   // 16384 lanes (x4 d)
    const int d4 = gid & 511;
    const int n  = (gid >> 9) & 15;
    const int b  = gid >> 13;
    const float an = -__expf(A_log[n]);
    float H0 = 0.f, H1 = 0.f, H2 = 0.f, H3 = 0.f;
    #pragma unroll 4
    for (int c = 0; c < NC; ++c) {
        size_t cidx = (size_t)(b * NC + c);
        float4 s  = ((const float4*)Sdl)[cidx * 512 + d4];
        size_t idx = (cidx * 16 + n) * 512 + d4;
        ushort4 he = ((const ushort4*)hend)[idx];
        ushort4 hs;
        hs.x = f2bf(H0); hs.y = f2bf(H1); hs.z = f2bf(H2); hs.w = f2bf(H3);
        ((ushort4*)hstart)[idx] = hs;              // start state for chunk c
        H0 = fmaf(__expf(an * s.x), H0, bf2f(he.x));
        H1 = fmaf(__expf(an * s.y), H1, bf2f(he.y));
        H2 = fmaf(__expf(an * s.z), H2, bf2f(he.z));
        H3 = fmaf(__expf(an * s.w), H3, bf2f(he.w));
    }
}

__global__ __launch_bounds__(256)
void scan_pass2(const u16* __restrict__ xcb, const u16* __restrict__ xpp,
                const float* __restrict__ W_dt, const float* __restrict__ b_dt,
                const float* __restrict__ A_log, const u16* __restrict__ Hstart,
                const float* __restrict__ Dp, const u16* __restrict__ xz,
                u16* __restrict__ ybuf) {
    const int c  = blockIdx.x;
    const int dg = blockIdx.y;
    const int b  = blockIdx.z;
    const int tid = threadIdx.x;
    const int d  = dg * 256 + tid;
    const int tok0 = b * 1024 + c * TC;

    __shared__ float xps[TC][36];
    stage_xp(xpp, xps, tok0, tid);
    __syncthreads();

    float a[16];
    bool fast = true;
    #pragma unroll
    for (int n = 0; n < 16; ++n) {
        a[n] = -__expf(A_log[n]);
        fast = fast && (__builtin_fabsf(a[n] + (float)(n + 1)) < 1e-3f * (n + 1));
    }

    const float wdt = W_dt[d];
    const float bdt = b_dt[d];

    float h[16];
    #pragma unroll
    for (int n = 0; n < 16; ++n)
        h[n] = bf2f(Hstart[((size_t)((b * NC + c) * 16 + n)) * 2048 + d]);

    const float Dd = Dp[d];
    for (int t = 0; t < TC; ++t) {
        const int tok = tok0 + t;
        const float dl = softplus_f(xps[t][0] * wdt + bdt);
        const float xv = bf2f(xcb[(size_t)tok * 2048 + d]);
        const float wv = dl * xv;
        if (fast) {
            float dA[16];
            pow_tree(__expf(-dl), dA);
            #pragma unroll
            for (int n = 0; n < 16; ++n)
                h[n] = fmaf(dA[n], h[n], wv * xps[t][1 + n]);
        } else {
            #pragma unroll
            for (int n = 0; n < 16; ++n)
                h[n] = fmaf(__expf(dl * a[n]), h[n], wv * xps[t][1 + n]);
        }
        float y0 = 0.f, y1 = 0.f, y2 = 0.f, y3 = 0.f;
        #pragma unroll
        for (int n = 0; n < 16; n += 4) {
            y0 = fmaf(h[n + 0], xps[t][17 + n + 0], y0);
            y1 = fmaf(h[n + 1], xps[t][17 + n + 1], y1);
            y2 = fmaf(h[n + 2], xps[t][17 + n + 2], y2);
            y3 = fmaf(h[n + 3], xps[t][17 + n + 3], y3);
        }
        float y = (y0 + y1) + (y2 + y3);
        y = fmaf(Dd, xv, y);
        float zv = bf2f(xz[(size_t)tok * 4096 + 2048 + d]);
        float sz = zv / (1.f + __expf(-zv));
        ybuf[(size_t)tok * 2048 + d] = f2bf(y * sz);
    }
}

// ---------------------------------------------------------------------------
extern "C" void kernel_launch(void* const* d_in, const int* in_sizes, int n_in,
                              void* d_out, int out_size, void* d_ws, size_t ws_size,
                              hipStream_t stream) {
    const float* x       = (const float*)d_in[0];
    const float* W_in    = (const float*)d_in[1];
    const float* conv_w  = (const float*)d_in[2];
    const float* conv_b  = (const float*)d_in[3];
    const float* W_xproj = (const float*)d_in[4];
    const float* W_dt    = (const float*)d_in[5];
    const float* b_dt    = (const float*)d_in[6];
    const float* A_log   = (const float*)d_in[7];
    const float* Dp      = (const float*)d_in[8];
    const float* W_out   = (const float*)d_in[9];
    float* out = (float*)d_out;                     // [2][1024][1024] f32

    char* ws = (char*)d_ws;
    size_t off = 0;
    auto alloc = [&](size_t bytes) -> void* {
        void* p = ws + off;
        off += (bytes + 255) & ~(size_t)255;
        return p;
    };

    u16*   xbf    = (u16*)  alloc((size_t)NTOK * 1024 * 2);
    u16*   xz     = (u16*)  alloc((size_t)NTOK * 4096 * 2);
    u16*   WinT   = (u16*)  alloc((size_t)4096 * 1024 * 2);
    u16*   WoutT  = (u16*)  alloc((size_t)1024 * 2048 * 2);
    u16*   WxpT   = (u16*)  alloc((size_t)128 * 2048 * 2);
    u16*   xcb    = (u16*)  alloc((size_t)NTOK * 2048 * 2);
    u16*   xpp    = (u16*)  alloc((size_t)XPP_PARTS * NTOK * 128 * 2); // 8.4 MB
    u16*   ybuf   = (u16*)  alloc((size_t)NTOK * 2048 * 2);
    float* Sdl    = (float*)alloc((size_t)2 * NC * 2048 * 4);
    u16*   hend   = (u16*)  alloc((size_t)2 * NC * 16 * 2048 * 2);  //  8.4 MB
    u16*   hstart = (u16*)  alloc((size_t)2 * NC * 16 * 2048 * 2);  //  8.4 MB
    u16*   op     = (u16*)  alloc((size_t)4 * NTOK * 1024 * 2);     // 16.8 MB

    const int ws_ok = (off <= ws_size);   // ws = 256 MiB; total ~85 MB
    if (ws_ok) {
        // fused prep: cast x (float4), transpose W_in/W_out, pad W_xproj
        prep_all<<<9216, 256, 0, stream>>>(x, W_in, W_out, W_xproj,
                                           xbf, WinT, WoutT, WxpT);

        // GEMM1: xz = xbf @ W_in (bf16 out), 512 blocks, 16 K-rounds
        gemm_bt<2><<<dim3(16, 32, 1), 256, 0, stream>>>(xbf, WinT, xz,
                                                        2048, 4096, 1024);

        // xproj with fused conv+SiLU (R4): writes xcb + bf16 xpp partials.
        xproj_conv<<<dim3(16, 1, XPP_PARTS), 256, 0, stream>>>(
            xz, conv_w, conv_b, WxpT, xcb, xpp);

        // chunked scan (NC=64: 1024 blocks/pass, 4 blk/CU — bracketed opt)
        scan_pass1<<<dim3(NC, 8, 2), 256, 0, stream>>>(xcb, xpp, W_dt, b_dt, A_log,
                                                       Sdl, hend);
        scan_combine<<<128, 128, 0, stream>>>(Sdl, A_log, hend, hstart);
        scan_pass2<<<dim3(NC, 8, 2), 256, 0, stream>>>(xcb, xpp, W_dt, b_dt, A_log,
                                                       hstart, Dp, xz, ybuf);

        // GEMM2: split-K=4 bf16 partials (R5), then bf16 reduce into d_out
        gemm_bt<0><<<dim3(16, 8, 4), 256, 0, stream>>>(ybuf, WoutT, op,
                                                       2048, 1024, 2048);
        reduce_parts_bf16<<<(NTOK * 1024 / 8) / 256, 256, 0, stream>>>(
            op, out, NTOK * 1024 / 8, 4);
    }
}